// Round 1
// baseline (583.669 us; speedup 1.0000x reference)
//
#include <hip/hip_runtime.h>
#include <hip/hip_bf16.h>

typedef __attribute__((ext_vector_type(8))) short bf16x8;
typedef __attribute__((ext_vector_type(4))) float f32x4;

#define AS1C(p) ((const __attribute__((address_space(1))) void*)(p))
#define AS3(p)  ((__attribute__((address_space(3))) void*)(p))

// ---------------------------------------------------------------------------
// Kernel 1: Hadamard-rotate (FWHT/sqrt(32)) + MXFP4 quant-dequant -> bf16
// One thread per 32-element group.
// ---------------------------------------------------------------------------
__global__ void rotquant_kernel(const float* __restrict__ in,
                                unsigned short* __restrict__ out, int ngroups) {
    int g = blockIdx.x * blockDim.x + threadIdx.x;
    if (g >= ngroups) return;

    const float4* p = (const float4*)(in + (size_t)g * 32);
    float v[32];
#pragma unroll
    for (int i = 0; i < 8; ++i) {
        float4 q = p[i];
        v[4 * i + 0] = q.x; v[4 * i + 1] = q.y;
        v[4 * i + 2] = q.z; v[4 * i + 3] = q.w;
    }

    // FWHT (Sylvester Hadamard), 5 butterfly stages, fully unrolled
#pragma unroll
    for (int s = 1; s < 32; s <<= 1) {
#pragma unroll
        for (int i = 0; i < 32; ++i) {
            if (!(i & s)) {
                float a = v[i], b = v[i + s];
                v[i] = a + b;
                v[i + s] = a - b;
            }
        }
    }

    const float INV = 0.17677669529663687f; // 1/sqrt(32)
    float amax = 0.f;
#pragma unroll
    for (int i = 0; i < 32; ++i) {
        v[i] *= INV;
        amax = fmaxf(amax, fabsf(v[i]));
    }

    // e = floor(log2(max(amax, 2^-126))) - 2, clipped to [-127, 127].
    // Exact via exponent-field extraction (amax >= 0 so no sign bit).
    int ex = (int)(__float_as_uint(amax) >> 23) - 127;
    if (ex < -126) ex = -126;     // zero/subnormal -> -126
    int e = ex - 2;
    if (e < -127) e = -127;
    float scale  = __uint_as_float((unsigned)(e + 127) << 23);   // 2^e
    float rscale = __uint_as_float((unsigned)(127 - e) << 23);   // 2^-e (exact)

    __attribute__((aligned(16))) unsigned short o[32];
#pragma unroll
    for (int i = 0; i < 32; ++i) {
        float s = v[i] * rscale;              // == v / scale exactly
        float a = fminf(fabsf(s), 6.0f);
        // idx = sum(a > mids), grid lookup via select chain (strict >, ties down)
        float q = a > 0.25f ? (a > 0.75f ? (a > 1.25f ? (a > 1.75f ?
                  (a > 2.5f ? (a > 3.5f ? (a > 5.0f ? 6.f : 4.f) : 3.f) : 2.f)
                  : 1.5f) : 1.f) : 0.5f) : 0.f;
        float r = copysignf(q, s) * scale;    // exact in f32 and bf16
        o[i] = (unsigned short)(__float_as_uint(r) >> 16); // exact bf16 truncation
    }

    unsigned short* op = out + (size_t)g * 32;
#pragma unroll
    for (int i = 0; i < 4; ++i)
        ((bf16x8*)op)[i] = *(const bf16x8*)&o[8 * i];
}

// ---------------------------------------------------------------------------
// Kernel 2: C[M,N] = A[M,K](bf16) * B[N,K](bf16)^T + bias[N], f32 out
// m97 structure: 128x128 tile, BK=32, 4 waves (2x2), 4x4 16x16x32 frags/wave,
// global_load_lds width 16, 2-barrier loop, XCD-aware block swizzle.
// ---------------------------------------------------------------------------
#define GBM 128
#define GBN 128
#define GBK 32

__global__ void gemm_bt_kernel(const unsigned short* __restrict__ A,
                               const unsigned short* __restrict__ B,
                               const float* __restrict__ bias,
                               float* __restrict__ C,
                               int M, int N, int K) {
    __shared__ unsigned short sA[GBM * GBK];
    __shared__ unsigned short sB[GBN * GBK];

    int nbn = N / GBN;
    int nwg = (M / GBM) * nbn;
    int bid = blockIdx.x;
    int swz;
    if ((nwg & 7) == 0) {                   // bijective XCD swizzle
        int cpx = nwg >> 3;
        swz = (bid & 7) * cpx + (bid >> 3);
    } else {
        swz = bid;
    }
    int bm = swz / nbn, bn = swz % nbn;

    int t = threadIdx.x;
    int lane = t & 63;
    int wid = t >> 6;
    int wr = wid >> 1, wc = wid & 1;        // 2x2 wave grid, 64x64 out each
    int fr = lane & 15, fq = lane >> 4;     // fragment row / k-chunk

    f32x4 acc[4][4] = {};

    // staging: thread t covers LDS bytes t*16 (linear), rows t>>2, kchunk t&3
    const unsigned short* gA = A + (size_t)bm * GBM * K + (size_t)(t >> 2) * K + (t & 3) * 8;
    const unsigned short* gB = B + (size_t)bn * GBN * K + (size_t)(t >> 2) * K + (t & 3) * 8;
    unsigned short* sAp = sA + t * 8;
    unsigned short* sBp = sB + t * 8;
    const size_t rowStep = (size_t)64 * K;

    for (int kb = 0; kb < K; kb += GBK) {
        __syncthreads();  // previous compute done before overwrite
        __builtin_amdgcn_global_load_lds(AS1C(gA + kb),           AS3(sAp),        16, 0, 0);
        __builtin_amdgcn_global_load_lds(AS1C(gA + kb + rowStep), AS3(sAp + 2048), 16, 0, 0);
        __builtin_amdgcn_global_load_lds(AS1C(gB + kb),           AS3(sBp),        16, 0, 0);
        __builtin_amdgcn_global_load_lds(AS1C(gB + kb + rowStep), AS3(sBp + 2048), 16, 0, 0);
        __syncthreads();  // compiler drains vmcnt before s_barrier

        bf16x8 af[4], bfr[4];
#pragma unroll
        for (int m = 0; m < 4; ++m)
            af[m] = *(const bf16x8*)&sA[(wr * 64 + m * 16 + fr) * GBK + fq * 8];
#pragma unroll
        for (int n = 0; n < 4; ++n)
            bfr[n] = *(const bf16x8*)&sB[(wc * 64 + n * 16 + fr) * GBK + fq * 8];

#pragma unroll
        for (int m = 0; m < 4; ++m)
#pragma unroll
            for (int n = 0; n < 4; ++n)
                acc[m][n] = __builtin_amdgcn_mfma_f32_16x16x32_bf16(
                    af[m], bfr[n], acc[m][n], 0, 0, 0);
    }

    // C/D layout (verified m89/m91): col = lane&15, row = (lane>>4)*4 + reg
    int row0 = bm * GBM + wr * 64 + fq * 4;
    int col0 = bn * GBN + wc * 64 + fr;
#pragma unroll
    for (int m = 0; m < 4; ++m) {
#pragma unroll
        for (int n = 0; n < 4; ++n) {
            int c = col0 + n * 16;
            float bv = bias[c];
#pragma unroll
            for (int j = 0; j < 4; ++j) {
                int r = row0 + m * 16 + j;
                C[(size_t)r * N + c] = acc[m][n][j] + bv;
            }
        }
    }
}

// ---------------------------------------------------------------------------
extern "C" void kernel_launch(void* const* d_in, const int* in_sizes, int n_in,
                              void* d_out, int out_size, void* d_ws, size_t ws_size,
                              hipStream_t stream) {
    const float* x    = (const float*)d_in[0];
    const float* w    = (const float*)d_in[1];
    const float* bias = (const float*)d_in[2];
    // d_in[3] (hadamard matrix) is Sylvester/sqrt(32): implemented as FWHT.

    int N = in_sizes[2];            // 4096
    int K = in_sizes[1] / N;        // 4096
    int M = in_sizes[0] / K;        // 8192

    unsigned short* xq = (unsigned short*)d_ws;
    unsigned short* wq = xq + (size_t)M * K;

    int ngx = (int)(((size_t)M * K) / 32);
    int ngw = (int)(((size_t)N * K) / 32);

    rotquant_kernel<<<dim3((ngx + 255) / 256), dim3(256), 0, stream>>>(x, xq, ngx);
    rotquant_kernel<<<dim3((ngw + 255) / 256), dim3(256), 0, stream>>>(w, wq, ngw);

    int grid = (M / GBM) * (N / GBN);
    gemm_bt_kernel<<<dim3(grid), dim3(256), 0, stream>>>(xq, wq, bias, (float*)d_out, M, N, K);
}